// Round 17
// baseline (272.653 us; speedup 1.0000x reference)
//
#include <hip/hip_runtime.h>
#include <hip/hip_bf16.h>

typedef __attribute__((ext_vector_type(8))) short short8;   // 8 bf16 (4 VGPRs) — MFMA A/B frag
typedef __attribute__((ext_vector_type(4))) float f32x4;    // MFMA C/D frag

#define DDIM 256
#define WROW 257
#define WSTRIDE 66049  // 257*257
#define WT3_N 36864    // shorts per n: 36 slabs * 1024

__device__ __forceinline__ unsigned short f2bf(float f) {
    unsigned int u = __float_as_uint(f);
    u += 0x7fff + ((u >> 16) & 1);   // RNE (finite values)
    return (unsigned short)(u >> 16);
}
__device__ __forceinline__ float bf2f(unsigned short s) {
    return __uint_as_float(((unsigned int)s) << 16);
}

// ======================= FAST PATH =======================

// Symmetrized, pre-scaled W in SLAB layout + fused v/d extraction.
//   slab(jt,kk) = jt*(jt+1)/2 + kk   (kk <= jt, 36 slabs)
//   Wt3[n][slab][half][lane(qw*16+r15)][kr] = s*(A[k][j]+A[j][k])
// R17: one (slab,half) chunk per wave; lane l emits the exact short8 that pn's
// lane l consumes -> ONE dense 16B store (was 8x 4B stride-32B scatter).
__global__ __launch_bounds__(256) void conv_w3_kernel(
    const float* __restrict__ Wf, unsigned short* __restrict__ Wt3,
    float* __restrict__ Vt, float* __restrict__ Dv)
{
    __shared__ float tKJ[64][65];   // A[tk*64+r][tj*64+c]
    __shared__ float tJK[64][65];   // A[tj*64+r][tk*64+c]
    const int TJ[10] = {0,1,1,2,2,2,3,3,3,3};
    const int TK[10] = {0,0,1,0,1,2,0,1,2,3};
    const int tid = threadIdx.x;
    const int n   = blockIdx.y;
    const int tj  = TJ[blockIdx.x];
    const int tk  = TK[blockIdx.x];
    const float* Wn = Wf + (size_t)n * WSTRIDE;
    if (blockIdx.x == 0) {   // fused conv_v (one block per n)
        int j = tid;
        Vt[n * 256 + j] = Wn[(size_t)j * WROW + 256] + Wn[65792 + j];
        if (j == 0) Dv[n] = Wn[66048];
    }
    #pragma unroll
    for (int it = 0; it < 4; ++it) {
        int idx = it * 256 + tid;            // 0..1023 float4 slots per tile
        int r   = idx >> 4;                  // row 0..63
        int c4  = (idx & 15) * 4;            // col 0,4,..,60
        float4 vKJ = *reinterpret_cast<const float4*>(&Wn[(size_t)(tk * 64 + r) * WROW + tj * 64 + c4]);
        float4 vJK = *reinterpret_cast<const float4*>(&Wn[(size_t)(tj * 64 + r) * WROW + tk * 64 + c4]);
        tKJ[r][c4 + 0] = vKJ.x; tKJ[r][c4 + 1] = vKJ.y; tKJ[r][c4 + 2] = vKJ.z; tKJ[r][c4 + 3] = vKJ.w;
        tJK[r][c4 + 0] = vJK.x; tJK[r][c4 + 1] = vJK.y; tJK[r][c4 + 2] = vJK.z; tJK[r][c4 + 3] = vJK.w;
    }
    __syncthreads();
    const int wv = tid >> 6, lane = tid & 63;
    unsigned short* out = Wt3 + (size_t)n * WT3_N;
    // enumerate (jtl,kkl,half) chunks with global kk<=jt (8 off-diag, 6 diag)
    int ch[8]; int nch = 0;
    #pragma unroll
    for (int jtl = 0; jtl < 2; ++jtl)
        #pragma unroll
        for (int kkl = 0; kkl < 2; ++kkl) {
            if (tk * 2 + kkl <= tj * 2 + jtl) {
                ch[nch++] = jtl * 4 + kkl * 2 + 0;
                ch[nch++] = jtl * 4 + kkl * 2 + 1;
            }
        }
    for (int c = wv; c < nch; c += 4) {
        const int jtl = ch[c] >> 2, kkl = (ch[c] >> 1) & 1, half = ch[c] & 1;
        const int jtg = tj * 2 + jtl, kkg = tk * 2 + kkl;
        const float sc = (kkg == jtg) ? 0.5f : 1.0f;
        const int jl = jtl * 32 + half * 16 + (lane & 15);   // j within tile
        const int k0 = kkl * 32 + (lane >> 4) * 8;           // k-octet within tile
        unsigned int w[4];
        #pragma unroll
        for (int t = 0; t < 4; ++t) {
            float lo = sc * (tKJ[k0 + 2 * t][jl]     + tJK[jl][k0 + 2 * t]);
            float hi = sc * (tKJ[k0 + 2 * t + 1][jl] + tJK[jl][k0 + 2 * t + 1]);
            w[t] = (unsigned)f2bf(lo) | ((unsigned)f2bf(hi) << 16);
        }
        size_t sidx = (size_t)(jtg * (jtg + 1) / 2 + kkg) * 1024 + half * 512 + lane * 8;
        *reinterpret_cast<uint4*>(out + sidx) = make_uint4(w[0], w[1], w[2], w[3]);
    }
}

// Epilogue gather: Xe2[bt][jt][m][lane] = short8 { x[row(m,qw,r)][jA] r=0..3, x[row][jB] r=0..3 }
__device__ __forceinline__ void xe_gather3(const unsigned short* T, unsigned short* Xe2,
                                           int bx, int tid) {
    const int lane = tid & 63, g = tid >> 6, qw = (tid >> 4) & 3, r15 = tid & 15;
    #pragma unroll
    for (int it = 0; it < 16; ++it) {
        int c  = g * 16 + it;        // flat (h, jt, m) in [0,64)
        int h  = c >> 5;
        int jt = (c >> 2) & 7;
        int m  = c & 3;
        int rbase = h * 64 + m * 16 + qw * 4;
        int jA = jt * 32 + r15;
        unsigned int u0 = T[(rbase + 0) * 256 + jA];
        unsigned int u1 = T[(rbase + 1) * 256 + jA];
        unsigned int u2 = T[(rbase + 2) * 256 + jA];
        unsigned int u3 = T[(rbase + 3) * 256 + jA];
        unsigned int v0 = T[(rbase + 0) * 256 + jA + 16];
        unsigned int v1 = T[(rbase + 1) * 256 + jA + 16];
        unsigned int v2 = T[(rbase + 2) * 256 + jA + 16];
        unsigned int v3 = T[(rbase + 3) * 256 + jA + 16];
        uint4 w = make_uint4(u0 | (u1 << 16), u2 | (u3 << 16),
                             v0 | (v1 << 16), v2 | (v3 << 16));
        *reinterpret_cast<uint4*>(Xe2 + ((size_t)(bx * 2 + h) * 16384 + jt * 2048 + m * 512 + lane * 8)) = w;
    }
}

// Layer-1 input prep: X f32 row-major -> Xbf (bf16 row-major) + Xe2
__global__ __launch_bounds__(256) void conv_x_rm_kernel(
    const float* __restrict__ X, unsigned short* __restrict__ Xbf, unsigned short* __restrict__ Xe2)
{
    __shared__ __align__(16) unsigned short T[128 * 256];
    const int tid = threadIdx.x;
    const int b0 = blockIdx.x * 128;
    const float4* Xv = reinterpret_cast<const float4*>(X + (size_t)b0 * 256);
    uint2* Xo = reinterpret_cast<uint2*>(Xbf + (size_t)b0 * 256);
    #pragma unroll
    for (int it = 0; it < 32; ++it) {
        int idx4 = it * 256 + tid;
        float4 v = Xv[idx4];
        uint2 p;
        p.x = (unsigned)f2bf(v.x) | ((unsigned)f2bf(v.y) << 16);
        p.y = (unsigned)f2bf(v.z) | ((unsigned)f2bf(v.w) << 16);
        *reinterpret_cast<uint2*>(&T[idx4 * 4]) = p;
        Xo[idx4] = p;
    }
    __syncthreads();
    xe_gather3(T, Xe2, blockIdx.x, tid);
}

// Layer-2/3 input prep: Ht bf16 [256][2048] (k-major) -> Xbf row-major + Xe2
__global__ __launch_bounds__(256) void conv_x_tr_kernel(
    const unsigned short* __restrict__ Hsrc, unsigned short* __restrict__ Xbf,
    unsigned short* __restrict__ Xe2)
{
    __shared__ __align__(16) unsigned short T[128 * 256];
    const int tid = threadIdx.x;
    const int b0 = blockIdx.x * 128;
    #pragma unroll
    for (int it = 0; it < 64; ++it) {
        int lin = it * 256 + tid;
        int k = lin >> 6, bp = lin & 63;
        unsigned int v = *reinterpret_cast<const unsigned int*>(Hsrc + (size_t)k * 2048 + b0 + bp * 2);
        T[(bp * 2) * 256 + k]     = (unsigned short)(v & 0xffff);
        T[(bp * 2 + 1) * 256 + k] = (unsigned short)(v >> 16);
    }
    __syncthreads();
    uint4* Xo = reinterpret_cast<uint4*>(Xbf + (size_t)b0 * 256);
    #pragma unroll
    for (int it = 0; it < 16; ++it) {   // 4096 uint4 per 128x256 tile
        int idx8 = it * 256 + tid;
        Xo[idx8] = *reinterpret_cast<uint4*>(&T[idx8 * 8]);
    }
    xe_gather3(T, Xe2, blockIdx.x, tid);
}

// pn10 (R13 structure — 56.3 us/layer at (256,2)): block = 4 waves, BM=64; wave wv
// computes the FULL triangle for n = ng*4+wv. Slab-layout W (dense 1KB bursts),
// depth-4 named prefetch, jt loop NOT unrolled (R9/R10: full unroll -> spill).
// R17: min-waves 3 — pn10 uses only 64 arch regs < the 84-arch cap at (256,3)
// (R7/R8 spills were ~120-reg kernels), so no spill expected; occupancy 33->~50%.
// TRIPWIRE: if WRITE_SIZE >> 1KB or pn dur regresses, revert to (256,2).
__global__ __launch_bounds__(256, 3) void pn10_kernel(
    const unsigned short* __restrict__ Xbf,  // [2048][256] bf16 row-major
    const unsigned short* __restrict__ Xe2,  // [32][8][4][64] short8 epilogue gather
    const unsigned short* __restrict__ Wt3,  // [256][36][2][64][8] slab-layout triangle
    const float* __restrict__ Vt,            // [256][256] v
    const float* __restrict__ Dv,            // [256] d
    unsigned short* __restrict__ Ht)         // [256][2048] bf16
{
    __shared__ __align__(16) char Xl[32768];  // bf16 [64][256], XOR-swizzled

    const int tid  = threadIdx.x;
    const int lane = tid & 63;
    const int wv   = tid >> 6;
    const int qw   = lane >> 4;
    const int r15  = lane & 15;

    const int fid = blockIdx.y * 32 + blockIdx.x;
    const int bt  = (fid >> 3) & 31;
    const int ng  = (fid & 7) + ((fid >> 8) << 3);
    const int n   = ng * 4 + wv;
    const int b0  = bt * 64;

    // ---- stage bf16 X tile (32 KB) with write-side XOR swizzle ----
    {
        const uint4* xs = reinterpret_cast<const uint4*>(Xbf + (size_t)b0 * 256);
        #pragma unroll
        for (int c = 0; c < 8; ++c) {
            int idx = c * 256 + tid;
            uint4 v = xs[idx];
            int L = idx * 16;
            int d = L ^ (((L >> 9) & 7) << 4);
            *reinterpret_cast<uint4*>(&Xl[d]) = v;
        }
    }

    const unsigned short* wp = Wt3 + (size_t)n * WT3_N + (size_t)lane * 8;
    const float* vn = Vt + n * 256;
    const unsigned short* xe = Xe2 + (size_t)bt * 16384 + (size_t)lane * 8;

    // ---- prologue: prefetch slabs 0..3 ----
    short8 bA0 = *reinterpret_cast<const short8*>(wp);
    short8 bB0 = *reinterpret_cast<const short8*>(wp + 512);
    short8 bA1 = *reinterpret_cast<const short8*>(wp + 1024);
    short8 bB1 = *reinterpret_cast<const short8*>(wp + 1024 + 512);
    short8 bA2 = *reinterpret_cast<const short8*>(wp + 2048);
    short8 bB2 = *reinterpret_cast<const short8*>(wp + 2048 + 512);
    short8 bA3 = *reinterpret_cast<const short8*>(wp + 3072);
    short8 bB3 = *reinterpret_cast<const short8*>(wp + 3072 + 512);

    // e and v for jt=0
    short8 e0 = *reinterpret_cast<const short8*>(xe);
    short8 e1 = *reinterpret_cast<const short8*>(xe + 512);
    short8 e2 = *reinterpret_cast<const short8*>(xe + 1024);
    short8 e3 = *reinterpret_cast<const short8*>(xe + 1536);
    float vA = vn[r15], vB = vn[16 + r15];

    float ps[4][4];
    f32x4 a0[4], a1[4];
    #pragma unroll
    for (int m = 0; m < 4; ++m) {
        a0[m] = f32x4{0.f, 0.f, 0.f, 0.f};
        a1[m] = f32x4{0.f, 0.f, 0.f, 0.f};
        #pragma unroll
        for (int r = 0; r < 4; ++r) ps[m][r] = 0.f;
    }

    int jt = 0, kk = 0;       // consume state
    int slab_pf = 4;          // next slab to prefetch

    __syncthreads();

    auto body = [&](short8& bA, short8& bB) {
        #pragma unroll
        for (int m = 0; m < 4; ++m) {
            const int row = m * 16 + r15;
            const int byte = (row * 512 + kk * 64 + qw * 16) ^ ((row & 7) << 4);
            short8 a = *reinterpret_cast<const short8*>(&Xl[byte]);
            a0[m] = __builtin_amdgcn_mfma_f32_16x16x32_bf16(a, bA, a0[m], 0, 0, 0);
            a1[m] = __builtin_amdgcn_mfma_f32_16x16x32_bf16(a, bB, a1[m], 0, 0, 0);
        }
        if (kk == jt) {        // wave-uniform: jt complete -> contract + advance
            #pragma unroll
            for (int r = 0; r < 4; ++r) {
                ps[0][r] += (a0[0][r] + vA) * bf2f((unsigned short)e0[r]) + (a1[0][r] + vB) * bf2f((unsigned short)e0[4 + r]);
                ps[1][r] += (a0[1][r] + vA) * bf2f((unsigned short)e1[r]) + (a1[1][r] + vB) * bf2f((unsigned short)e1[4 + r]);
                ps[2][r] += (a0[2][r] + vA) * bf2f((unsigned short)e2[r]) + (a1[2][r] + vB) * bf2f((unsigned short)e2[4 + r]);
                ps[3][r] += (a0[3][r] + vA) * bf2f((unsigned short)e3[r]) + (a1[3][r] + vB) * bf2f((unsigned short)e3[4 + r]);
            }
            #pragma unroll
            for (int m = 0; m < 4; ++m) {
                a0[m] = f32x4{0.f, 0.f, 0.f, 0.f};
                a1[m] = f32x4{0.f, 0.f, 0.f, 0.f};
            }
            jt += 1; kk = 0;
            const int jc = (jt < 8) ? jt : 7;   // clamp (tail values unused)
            e0 = *reinterpret_cast<const short8*>(xe + jc * 2048);
            e1 = *reinterpret_cast<const short8*>(xe + jc * 2048 + 512);
            e2 = *reinterpret_cast<const short8*>(xe + jc * 2048 + 1024);
            e3 = *reinterpret_cast<const short8*>(xe + jc * 2048 + 1536);
            vA = vn[jc * 32 + r15];
            vB = vn[jc * 32 + 16 + r15];
        } else {
            kk += 1;
        }
        // prefetch slab_pf (clamped; tail re-reads slab 35, L1-hot, discarded)
        const int sc = (slab_pf <= 35) ? slab_pf : 35;
        const unsigned short* pf = wp + (size_t)sc * 1024;
        bA = *reinterpret_cast<const short8*>(pf);
        bB = *reinterpret_cast<const short8*>(pf + 512);
        slab_pf += 1;
    };

    #pragma unroll 1   // 9 iters x 4 bodies = 36 steps; DO NOT fully unroll (spill)
    for (int i = 0; i < 9; ++i) {
        body(bA0, bB0);
        body(bA1, bB1);
        body(bA2, bB2);
        body(bA3, bB3);
    }

    // reduce over the 16 j-lanes (r15 bits)
    #pragma unroll
    for (int off = 1; off <= 8; off <<= 1)
        #pragma unroll
        for (int m = 0; m < 4; ++m)
            #pragma unroll
            for (int r = 0; r < 4; ++r) ps[m][r] += __shfl_xor(ps[m][r], off, 64);

    if (r15 == 0) {
        const float dn = Dv[n];
        #pragma unroll
        for (int m = 0; m < 4; ++m)
            #pragma unroll
            for (int r = 0; r < 4; ++r)
                Ht[(size_t)n * 2048 + b0 + m * 16 + qw * 4 + r] = f2bf(ps[m][r] + dn);
    }
}

__global__ __launch_bounds__(256) void out_tr_kernel(
    const unsigned short* __restrict__ H3, const float* __restrict__ w_out,
    const float* __restrict__ b_out, float* __restrict__ out)
{
    __shared__ float red2[256];
    const int tid = threadIdx.x;
    const int b = blockIdx.x * 128 + (tid & 127);
    const int half = tid >> 7;
    float s = 0.f;
    #pragma unroll 8
    for (int k = 0; k < 128; ++k) {
        int nn = half * 128 + k;
        s += bf2f(H3[(size_t)nn * 2048 + b]) * w_out[nn];
    }
    red2[tid] = s;
    __syncthreads();
    if (tid < 128) out[b] = red2[tid] + red2[tid + 128] + b_out[0];
}

// ======================= FALLBACK PATH (small ws) =======================

__global__ __launch_bounds__(256, 2) void pn_layer_kernel(
    const float* __restrict__ X, const float* __restrict__ W, float* __restrict__ H)
{
    __shared__ __align__(16) char Xl[64 * 256 * 2];
    __shared__ __align__(16) char Wl[2][256 * 32 * 2];
    const int tid  = threadIdx.x;
    const int lane = tid & 63;
    const int wv   = tid >> 6;
    const int qw   = lane >> 4;
    const int r15  = lane & 15;
    const int n  = blockIdx.y;
    const int b0 = blockIdx.x * 64;
    const float* Wn = W + (size_t)n * WSTRIDE;
    {
        const float4* Xv = reinterpret_cast<const float4*>(X + (size_t)b0 * DDIM);
        #pragma unroll
        for (int it = 0; it < 16; ++it) {
            int idx4 = tid + it * 256;
            int r = idx4 >> 6, c4 = idx4 & 63;
            float4 v = Xv[r * 64 + c4];
            uint2 p;
            p.x = (unsigned)f2bf(v.x) | ((unsigned)f2bf(v.y) << 16);
            p.y = (unsigned)f2bf(v.z) | ((unsigned)f2bf(v.w) << 16);
            int byte = (r * 512 + c4 * 8) ^ ((r & 7) << 4);
            *reinterpret_cast<uint2*>(&Xl[byte]) = p;
        }
    }
    f32x4 acc[4][4];
    #pragma unroll
    for (int nf = 0; nf < 4; ++nf) {
        int j = wv * 64 + nf * 16 + r15;
        float vj = Wn[(size_t)j * WROW + 256] + Wn[65792 + j];
        #pragma unroll
        for (int m = 0; m < 4; ++m) acc[m][nf] = f32x4{vj, vj, vj, vj};
    }
    auto stageW = [&](int buf, int kk) {
        const int k0 = kk * 32;
        const int j  = tid;
        float t[32];
        #pragma unroll
        for (int k = 0; k < 32; ++k) t[k] = Wn[(size_t)(k0 + k) * WROW + j];
        char* Wb = Wl[buf];
        #pragma unroll
        for (int g = 0; g < 4; ++g) {
            unsigned int p0 = (unsigned)f2bf(t[g*8+0]) | ((unsigned)f2bf(t[g*8+1]) << 16);
            unsigned int p1 = (unsigned)f2bf(t[g*8+2]) | ((unsigned)f2bf(t[g*8+3]) << 16);
            unsigned int p2 = (unsigned)f2bf(t[g*8+4]) | ((unsigned)f2bf(t[g*8+5]) << 16);
            unsigned int p3 = (unsigned)f2bf(t[g*8+6]) | ((unsigned)f2bf(t[g*8+7]) << 16);
            int byte = (j * 64 + g * 16) ^ ((j & 7) << 4);
            *reinterpret_cast<uint4*>(&Wb[byte]) = make_uint4(p0, p1, p2, p3);
        }
    };
    auto computeK = [&](int buf, int kk) {
        char* Wb = Wl[buf];
        short8 a[4], bbf[4];
        #pragma unroll
        for (int m = 0; m < 4; ++m) {
            int row = m * 16 + r15;
            int byte = (row * 512 + kk * 64 + qw * 16) ^ ((row & 7) << 4);
            a[m] = *reinterpret_cast<short8*>(&Xl[byte]);
        }
        #pragma unroll
        for (int nf = 0; nf < 4; ++nf) {
            int j = wv * 64 + nf * 16 + r15;
            int byte = (j * 64 + qw * 16) ^ ((j & 7) << 4);
            bbf[nf] = *reinterpret_cast<short8*>(&Wb[byte]);
        }
        #pragma unroll
        for (int m = 0; m < 4; ++m)
            #pragma unroll
            for (int nf = 0; nf < 4; ++nf)
                acc[m][nf] = __builtin_amdgcn_mfma_f32_16x16x32_bf16(a[m], bbf[nf], acc[m][nf], 0, 0, 0);
    };
    stageW(0, 0);
    int cur = 0;
    #pragma unroll
    for (int kk = 0; kk < 8; ++kk) {
        __syncthreads();
        if (kk < 7) stageW(cur ^ 1, kk + 1);
        computeK(cur, kk);
        cur ^= 1;
    }
    float ps[16];
    #pragma unroll
    for (int i = 0; i < 16; ++i) ps[i] = 0.f;
    #pragma unroll
    for (int m = 0; m < 4; ++m)
        #pragma unroll
        for (int nf = 0; nf < 4; ++nf) {
            int j = wv * 64 + nf * 16 + r15;
            #pragma unroll
            for (int r = 0; r < 4; ++r) {
                int brow = m * 16 + qw * 4 + r;
                int byte = (brow * 512 + j * 2) ^ ((brow & 7) << 4);
                float xv = bf2f(*reinterpret_cast<unsigned short*>(&Xl[byte]));
                ps[m * 4 + r] += acc[m][nf][r] * xv;
            }
        }
    #pragma unroll
    for (int off = 1; off <= 8; off <<= 1)
        #pragma unroll
        for (int i = 0; i < 16; ++i) ps[i] += __shfl_xor(ps[i], off, 64);
    __syncthreads();
    float* red = reinterpret_cast<float*>(Wl);
    if (r15 == 0) {
        #pragma unroll
        for (int m = 0; m < 4; ++m)
            #pragma unroll
            for (int r = 0; r < 4; ++r)
                red[wv * 64 + m * 16 + qw * 4 + r] = ps[m * 4 + r];
    }
    __syncthreads();
    if (tid < 64) {
        float s = red[tid] + red[64 + tid] + red[128 + tid] + red[192 + tid] + Wn[66048];
        H[(size_t)(b0 + tid) * DDIM + n] = s;
    }
}

__global__ __launch_bounds__(256) void out_kernel(
    const float* __restrict__ H, const float* __restrict__ w_out,
    const float* __restrict__ b_out, float* __restrict__ out)
{
    int b = blockIdx.x * 4 + (threadIdx.x >> 6);
    int lane = threadIdx.x & 63;
    const float* h = H + (size_t)b * 256;
    float s = 0.f;
    #pragma unroll
    for (int c = 0; c < 4; ++c) s += h[lane + c * 64] * w_out[lane + c * 64];
    #pragma unroll
    for (int off = 1; off < 64; off <<= 1) s += __shfl_xor(s, off, 64);
    if (lane == 0) out[b] = s + b_out[0];
}

extern "C" void kernel_launch(void* const* d_in, const int* in_sizes, int n_in,
                              void* d_out, int out_size, void* d_ws, size_t ws_size,
                              hipStream_t stream) {
    const float* x    = (const float*)d_in[0];
    const float* W1   = (const float*)d_in[1];
    const float* W2   = (const float*)d_in[2];
    const float* W3   = (const float*)d_in[3];
    const float* wout = (const float*)d_in[4];
    const float* bout = (const float*)d_in[5];
    float* out = (float*)d_out;

    const size_t WT3_BYTES = (size_t)256 * WT3_N * 2;      // 18.87 MB
    const size_t XB_BYTES  = (size_t)2048 * 256 * 2;       // 1 MB
    const size_t XE2_BYTES = (size_t)32 * 16384 * 2;       // 1 MB
    const size_t VT_BYTES  = 256 * 256 * 4;                // 256 KB
    const size_t DV_BYTES  = 1024;
    const size_t HT_BYTES  = (size_t)256 * 2048 * 2;       // 1 MB
    const size_t need = WT3_BYTES + XB_BYTES + XE2_BYTES + VT_BYTES + DV_BYTES + HT_BYTES; // ~22.1 MB

    dim3 blk(256, 1, 1);

    if (ws_size >= need) {
        char* p = (char*)d_ws;
        unsigned short* Wt3 = (unsigned short*)p;              p += WT3_BYTES;
        unsigned short* Xbf = (unsigned short*)p;              p += XB_BYTES;
        unsigned short* Xe2 = (unsigned short*)p;              p += XE2_BYTES;
        float*          Vt  = (float*)p;                       p += VT_BYTES;
        float*          Dv  = (float*)p;                       p += DV_BYTES;
        unsigned short* Ht  = (unsigned short*)p;

        const float* Ws[3] = {W1, W2, W3};

        dim3 wgrid(10, 256), lgrid(32, 64), xgrid(16);
        for (int L = 0; L < 3; ++L) {
            if (L == 0) conv_x_rm_kernel<<<xgrid, blk, 0, stream>>>(x, Xbf, Xe2);
            else        conv_x_tr_kernel<<<xgrid, blk, 0, stream>>>(Ht, Xbf, Xe2);
            conv_w3_kernel<<<wgrid, blk, 0, stream>>>(Ws[L], Wt3, Vt, Dv);
            pn10_kernel<<<lgrid, blk, 0, stream>>>(Xbf, Xe2, Wt3, Vt, Dv, Ht);
        }
        out_tr_kernel<<<xgrid, blk, 0, stream>>>(Ht, wout, bout, out);
    } else {
        float* h1 = (float*)d_ws;
        float* h2 = h1 + 2048 * 256;
        dim3 grid(32, 256);
        pn_layer_kernel<<<grid, blk, 0, stream>>>(x,  W1, h1);
        pn_layer_kernel<<<grid, blk, 0, stream>>>(h1, W2, h2);
        pn_layer_kernel<<<grid, blk, 0, stream>>>(h2, W3, h1);
        out_kernel<<<512, blk, 0, stream>>>(h1, wout, bout, out);
    }
}

// Round 18
// 260.079 us; speedup vs baseline: 1.0483x; 1.0483x over previous
//
#include <hip/hip_runtime.h>
#include <hip/hip_bf16.h>

typedef __attribute__((ext_vector_type(8))) short short8;   // 8 bf16 (4 VGPRs) — MFMA A/B frag
typedef __attribute__((ext_vector_type(4))) float f32x4;    // MFMA C/D frag

#define DDIM 256
#define WROW 257
#define WSTRIDE 66049  // 257*257
#define WT3_N 36864    // shorts per n: 36 slabs * 1024

__device__ __forceinline__ unsigned short f2bf(float f) {
    unsigned int u = __float_as_uint(f);
    u += 0x7fff + ((u >> 16) & 1);   // RNE (finite values)
    return (unsigned short)(u >> 16);
}
__device__ __forceinline__ float bf2f(unsigned short s) {
    return __uint_as_float(((unsigned int)s) << 16);
}

// ======================= FAST PATH =======================

// Symmetrized, pre-scaled W in SLAB layout + fused v/d extraction (R17 form).
__global__ __launch_bounds__(256) void conv_w3_kernel(
    const float* __restrict__ Wf, unsigned short* __restrict__ Wt3,
    float* __restrict__ Vt, float* __restrict__ Dv)
{
    __shared__ float tKJ[64][65];   // A[tk*64+r][tj*64+c]
    __shared__ float tJK[64][65];   // A[tj*64+r][tk*64+c]
    const int TJ[10] = {0,1,1,2,2,2,3,3,3,3};
    const int TK[10] = {0,0,1,0,1,2,0,1,2,3};
    const int tid = threadIdx.x;
    const int n   = blockIdx.y;
    const int tj  = TJ[blockIdx.x];
    const int tk  = TK[blockIdx.x];
    const float* Wn = Wf + (size_t)n * WSTRIDE;
    if (blockIdx.x == 0) {   // fused conv_v (one block per n)
        int j = tid;
        Vt[n * 256 + j] = Wn[(size_t)j * WROW + 256] + Wn[65792 + j];
        if (j == 0) Dv[n] = Wn[66048];
    }
    #pragma unroll
    for (int it = 0; it < 4; ++it) {
        int idx = it * 256 + tid;
        int r   = idx >> 4;
        int c4  = (idx & 15) * 4;
        float4 vKJ = *reinterpret_cast<const float4*>(&Wn[(size_t)(tk * 64 + r) * WROW + tj * 64 + c4]);
        float4 vJK = *reinterpret_cast<const float4*>(&Wn[(size_t)(tj * 64 + r) * WROW + tk * 64 + c4]);
        tKJ[r][c4 + 0] = vKJ.x; tKJ[r][c4 + 1] = vKJ.y; tKJ[r][c4 + 2] = vKJ.z; tKJ[r][c4 + 3] = vKJ.w;
        tJK[r][c4 + 0] = vJK.x; tJK[r][c4 + 1] = vJK.y; tJK[r][c4 + 2] = vJK.z; tJK[r][c4 + 3] = vJK.w;
    }
    __syncthreads();
    const int wv = tid >> 6, lane = tid & 63;
    unsigned short* out = Wt3 + (size_t)n * WT3_N;
    int ch[8]; int nch = 0;
    #pragma unroll
    for (int jtl = 0; jtl < 2; ++jtl)
        #pragma unroll
        for (int kkl = 0; kkl < 2; ++kkl) {
            if (tk * 2 + kkl <= tj * 2 + jtl) {
                ch[nch++] = jtl * 4 + kkl * 2 + 0;
                ch[nch++] = jtl * 4 + kkl * 2 + 1;
            }
        }
    for (int c = wv; c < nch; c += 4) {
        const int jtl = ch[c] >> 2, kkl = (ch[c] >> 1) & 1, half = ch[c] & 1;
        const int jtg = tj * 2 + jtl, kkg = tk * 2 + kkl;
        const float sc = (kkg == jtg) ? 0.5f : 1.0f;
        const int jl = jtl * 32 + half * 16 + (lane & 15);
        const int k0 = kkl * 32 + (lane >> 4) * 8;
        unsigned int w[4];
        #pragma unroll
        for (int t = 0; t < 4; ++t) {
            float lo = sc * (tKJ[k0 + 2 * t][jl]     + tJK[jl][k0 + 2 * t]);
            float hi = sc * (tKJ[k0 + 2 * t + 1][jl] + tJK[jl][k0 + 2 * t + 1]);
            w[t] = (unsigned)f2bf(lo) | ((unsigned)f2bf(hi) << 16);
        }
        size_t sidx = (size_t)(jtg * (jtg + 1) / 2 + kkg) * 1024 + half * 512 + lane * 8;
        *reinterpret_cast<uint4*>(out + sidx) = make_uint4(w[0], w[1], w[2], w[3]);
    }
}

// Epilogue gather: Xe2[bt][jt][m][lane] = short8 { x[row(m,qw,r)][jA] r=0..3, x[row][jB] r=0..3 }
__device__ __forceinline__ void xe_gather3(const unsigned short* T, unsigned short* Xe2,
                                           int bx, int tid) {
    const int lane = tid & 63, g = tid >> 6, qw = (tid >> 4) & 3, r15 = tid & 15;
    #pragma unroll
    for (int it = 0; it < 16; ++it) {
        int c  = g * 16 + it;        // flat (h, jt, m) in [0,64)
        int h  = c >> 5;
        int jt = (c >> 2) & 7;
        int m  = c & 3;
        int rbase = h * 64 + m * 16 + qw * 4;
        int jA = jt * 32 + r15;
        unsigned int u0 = T[(rbase + 0) * 256 + jA];
        unsigned int u1 = T[(rbase + 1) * 256 + jA];
        unsigned int u2 = T[(rbase + 2) * 256 + jA];
        unsigned int u3 = T[(rbase + 3) * 256 + jA];
        unsigned int v0 = T[(rbase + 0) * 256 + jA + 16];
        unsigned int v1 = T[(rbase + 1) * 256 + jA + 16];
        unsigned int v2 = T[(rbase + 2) * 256 + jA + 16];
        unsigned int v3 = T[(rbase + 3) * 256 + jA + 16];
        uint4 w = make_uint4(u0 | (u1 << 16), u2 | (u3 << 16),
                             v0 | (v1 << 16), v2 | (v3 << 16));
        *reinterpret_cast<uint4*>(Xe2 + ((size_t)(bx * 2 + h) * 16384 + jt * 2048 + m * 512 + lane * 8)) = w;
    }
}

// Layer-1 input prep: X f32 row-major -> Xbf (bf16 row-major) + Xe2
__global__ __launch_bounds__(256) void conv_x_rm_kernel(
    const float* __restrict__ X, unsigned short* __restrict__ Xbf, unsigned short* __restrict__ Xe2)
{
    __shared__ __align__(16) unsigned short T[128 * 256];
    const int tid = threadIdx.x;
    const int b0 = blockIdx.x * 128;
    const float4* Xv = reinterpret_cast<const float4*>(X + (size_t)b0 * 256);
    uint2* Xo = reinterpret_cast<uint2*>(Xbf + (size_t)b0 * 256);
    #pragma unroll
    for (int it = 0; it < 32; ++it) {
        int idx4 = it * 256 + tid;
        float4 v = Xv[idx4];
        uint2 p;
        p.x = (unsigned)f2bf(v.x) | ((unsigned)f2bf(v.y) << 16);
        p.y = (unsigned)f2bf(v.z) | ((unsigned)f2bf(v.w) << 16);
        *reinterpret_cast<uint2*>(&T[idx4 * 4]) = p;
        Xo[idx4] = p;
    }
    __syncthreads();
    xe_gather3(T, Xe2, blockIdx.x, tid);
}

// Layer-2/3 input prep: Ht bf16 [256][2048] (k-major) -> Xbf row-major + Xe2
__global__ __launch_bounds__(256) void conv_x_tr_kernel(
    const unsigned short* __restrict__ Hsrc, unsigned short* __restrict__ Xbf,
    unsigned short* __restrict__ Xe2)
{
    __shared__ __align__(16) unsigned short T[128 * 256];
    const int tid = threadIdx.x;
    const int b0 = blockIdx.x * 128;
    #pragma unroll
    for (int it = 0; it < 64; ++it) {
        int lin = it * 256 + tid;
        int k = lin >> 6, bp = lin & 63;
        unsigned int v = *reinterpret_cast<const unsigned int*>(Hsrc + (size_t)k * 2048 + b0 + bp * 2);
        T[(bp * 2) * 256 + k]     = (unsigned short)(v & 0xffff);
        T[(bp * 2 + 1) * 256 + k] = (unsigned short)(v >> 16);
    }
    __syncthreads();
    uint4* Xo = reinterpret_cast<uint4*>(Xbf + (size_t)b0 * 256);
    #pragma unroll
    for (int it = 0; it < 16; ++it) {   // 4096 uint4 per 128x256 tile
        int idx8 = it * 256 + tid;
        Xo[idx8] = *reinterpret_cast<uint4*>(&T[idx8 * 8]);
    }
    xe_gather3(T, Xe2, blockIdx.x, tid);
}

// pn13 (R18): DUAL-n per wave — wave wv computes n0 = ng*8+wv AND n1 = n0+4 over
// the same bt tile. Per body: 16 MFMA sharing ONE X-frag load, one addr chain, one
// state machine; contraction shares e-frags + cvts across both n. W prefetch depth
// 2 (reg budget); order consume -> contract -> prefetch keeps peak arch ~120 < 128.
// jt loop NOT unrolled (R9/R10). TRIPWIRE: WRITE_SIZE >> 1KB = spill -> revert R16.
__global__ __launch_bounds__(256, 2) void pn13_kernel(
    const unsigned short* __restrict__ Xbf,  // [2048][256] bf16 row-major
    const unsigned short* __restrict__ Xe2,  // [32][8][4][64] short8 epilogue gather
    const unsigned short* __restrict__ Wt3,  // [256][36][2][64][8] slab-layout triangle
    const float* __restrict__ Vt,            // [256][256] v
    const float* __restrict__ Dv,            // [256] d
    unsigned short* __restrict__ Ht)         // [256][2048] bf16
{
    __shared__ __align__(16) char Xl[32768];  // bf16 [64][256], XOR-swizzled

    const int tid  = threadIdx.x;
    const int lane = tid & 63;
    const int wv   = tid >> 6;
    const int qw   = lane >> 4;
    const int r15  = lane & 15;

    // grid (32,32) = 1024 blocks; XCD k handles ng === k (mod 8): W set ~2.4MB < L2.
    const int fid = blockIdx.y * 32 + blockIdx.x;
    const int bt  = (fid >> 3) & 31;
    const int ng  = (fid & 7) + ((fid >> 8) << 3);   // 0..31
    const int n0  = ng * 8 + wv;
    const int n1  = n0 + 4;
    const int b0  = bt * 64;

    // ---- stage bf16 X tile (32 KB) with write-side XOR swizzle ----
    {
        const uint4* xs = reinterpret_cast<const uint4*>(Xbf + (size_t)b0 * 256);
        #pragma unroll
        for (int c = 0; c < 8; ++c) {
            int idx = c * 256 + tid;
            uint4 v = xs[idx];
            int L = idx * 16;
            int d = L ^ (((L >> 9) & 7) << 4);
            *reinterpret_cast<uint4*>(&Xl[d]) = v;
        }
    }

    const unsigned short* wp0 = Wt3 + (size_t)n0 * WT3_N + (size_t)lane * 8;
    const unsigned short* wp1 = Wt3 + (size_t)n1 * WT3_N + (size_t)lane * 8;
    const float* vn0 = Vt + n0 * 256;
    const float* vn1 = Vt + n1 * 256;
    const unsigned short* xe = Xe2 + (size_t)bt * 16384 + (size_t)lane * 8;

    // ---- prologue: prefetch slabs 0,1 for both n (8 bufs) ----
    short8 A0a = *reinterpret_cast<const short8*>(wp0);
    short8 B0a = *reinterpret_cast<const short8*>(wp0 + 512);
    short8 C0a = *reinterpret_cast<const short8*>(wp1);
    short8 D0a = *reinterpret_cast<const short8*>(wp1 + 512);
    short8 A0b = *reinterpret_cast<const short8*>(wp0 + 1024);
    short8 B0b = *reinterpret_cast<const short8*>(wp0 + 1024 + 512);
    short8 C0b = *reinterpret_cast<const short8*>(wp1 + 1024);
    short8 D0b = *reinterpret_cast<const short8*>(wp1 + 1024 + 512);

    float ps0[4][4], ps1[4][4];
    f32x4 q0[4], q1[4], q2[4], q3[4];
    #pragma unroll
    for (int m = 0; m < 4; ++m) {
        q0[m] = f32x4{0.f, 0.f, 0.f, 0.f};
        q1[m] = f32x4{0.f, 0.f, 0.f, 0.f};
        q2[m] = f32x4{0.f, 0.f, 0.f, 0.f};
        q3[m] = f32x4{0.f, 0.f, 0.f, 0.f};
        #pragma unroll
        for (int r = 0; r < 4; ++r) { ps0[m][r] = 0.f; ps1[m][r] = 0.f; }
    }

    int jt = 0, kk = 0;       // consume state
    int slab_pf = 2;          // next slab to prefetch

    __syncthreads();

    auto body = [&](short8& bA, short8& bB, short8& cA, short8& cB) {
        const bool last = (kk == jt);
        // e-prefetch for the contraction (issued before MFMAs; ~80cyc cover; L2-hot)
        short8 e0, e1, e2, e3;
        if (last) {
            const unsigned short* ep = xe + jt * 2048;
            e0 = *reinterpret_cast<const short8*>(ep);
            e1 = *reinterpret_cast<const short8*>(ep + 512);
            e2 = *reinterpret_cast<const short8*>(ep + 1024);
            e3 = *reinterpret_cast<const short8*>(ep + 1536);
        }
        #pragma unroll
        for (int m = 0; m < 4; ++m) {
            const int row = m * 16 + r15;
            const int byte = (row * 512 + kk * 64 + qw * 16) ^ ((row & 7) << 4);
            short8 a = *reinterpret_cast<const short8*>(&Xl[byte]);
            q0[m] = __builtin_amdgcn_mfma_f32_16x16x32_bf16(a, bA, q0[m], 0, 0, 0);
            q1[m] = __builtin_amdgcn_mfma_f32_16x16x32_bf16(a, bB, q1[m], 0, 0, 0);
            q2[m] = __builtin_amdgcn_mfma_f32_16x16x32_bf16(a, cA, q2[m], 0, 0, 0);
            q3[m] = __builtin_amdgcn_mfma_f32_16x16x32_bf16(a, cB, q3[m], 0, 0, 0);
        }
        if (last) {            // wave-uniform: jt complete -> contract both n + advance
            const float vA0 = vn0[jt * 32 + r15], vB0 = vn0[jt * 32 + 16 + r15];
            const float vA1 = vn1[jt * 32 + r15], vB1 = vn1[jt * 32 + 16 + r15];
            short8 ee[4] = {e0, e1, e2, e3};
            #pragma unroll
            for (int m = 0; m < 4; ++m) {
                #pragma unroll
                for (int r = 0; r < 4; ++r) {
                    const float exA = bf2f((unsigned short)ee[m][r]);
                    const float exB = bf2f((unsigned short)ee[m][4 + r]);
                    ps0[m][r] += (q0[m][r] + vA0) * exA + (q1[m][r] + vB0) * exB;
                    ps1[m][r] += (q2[m][r] + vA1) * exA + (q3[m][r] + vB1) * exB;
                }
                q0[m] = f32x4{0.f, 0.f, 0.f, 0.f};
                q1[m] = f32x4{0.f, 0.f, 0.f, 0.f};
                q2[m] = f32x4{0.f, 0.f, 0.f, 0.f};
                q3[m] = f32x4{0.f, 0.f, 0.f, 0.f};
            }
            jt += 1; kk = 0;
        } else {
            kk += 1;
        }
        // prefetch slab_pf into this stage's bufs (clamped tail; L1-hot, discarded)
        const int sc = (slab_pf <= 35) ? slab_pf : 35;
        bA = *reinterpret_cast<const short8*>(wp0 + (size_t)sc * 1024);
        bB = *reinterpret_cast<const short8*>(wp0 + (size_t)sc * 1024 + 512);
        cA = *reinterpret_cast<const short8*>(wp1 + (size_t)sc * 1024);
        cB = *reinterpret_cast<const short8*>(wp1 + (size_t)sc * 1024 + 512);
        slab_pf += 1;
    };

    #pragma unroll 1   // 18 iters x 2 bodies = 36 steps; DO NOT fully unroll (spill)
    for (int i = 0; i < 18; ++i) {
        body(A0a, B0a, C0a, D0a);
        body(A0b, B0b, C0b, D0b);
    }

    // reduce over the 16 j-lanes (r15 bits)
    #pragma unroll
    for (int off = 1; off <= 8; off <<= 1)
        #pragma unroll
        for (int m = 0; m < 4; ++m)
            #pragma unroll
            for (int r = 0; r < 4; ++r) {
                ps0[m][r] += __shfl_xor(ps0[m][r], off, 64);
                ps1[m][r] += __shfl_xor(ps1[m][r], off, 64);
            }

    if (r15 == 0) {
        const float dn0 = Dv[n0], dn1 = Dv[n1];
        #pragma unroll
        for (int m = 0; m < 4; ++m)
            #pragma unroll
            for (int r = 0; r < 4; ++r) {
                Ht[(size_t)n0 * 2048 + b0 + m * 16 + qw * 4 + r] = f2bf(ps0[m][r] + dn0);
                Ht[(size_t)n1 * 2048 + b0 + m * 16 + qw * 4 + r] = f2bf(ps1[m][r] + dn1);
            }
    }
}

__global__ __launch_bounds__(256) void out_tr_kernel(
    const unsigned short* __restrict__ H3, const float* __restrict__ w_out,
    const float* __restrict__ b_out, float* __restrict__ out)
{
    __shared__ float red2[256];
    const int tid = threadIdx.x;
    const int b = blockIdx.x * 128 + (tid & 127);
    const int half = tid >> 7;
    float s = 0.f;
    #pragma unroll 8
    for (int k = 0; k < 128; ++k) {
        int nn = half * 128 + k;
        s += bf2f(H3[(size_t)nn * 2048 + b]) * w_out[nn];
    }
    red2[tid] = s;
    __syncthreads();
    if (tid < 128) out[b] = red2[tid] + red2[tid + 128] + b_out[0];
}

// ======================= FALLBACK PATH (small ws) =======================

__global__ __launch_bounds__(256, 2) void pn_layer_kernel(
    const float* __restrict__ X, const float* __restrict__ W, float* __restrict__ H)
{
    __shared__ __align__(16) char Xl[64 * 256 * 2];
    __shared__ __align__(16) char Wl[2][256 * 32 * 2];
    const int tid  = threadIdx.x;
    const int lane = tid & 63;
    const int wv   = tid >> 6;
    const int qw   = lane >> 4;
    const int r15  = lane & 15;
    const int n  = blockIdx.y;
    const int b0 = blockIdx.x * 64;
    const float* Wn = W + (size_t)n * WSTRIDE;
    {
        const float4* Xv = reinterpret_cast<const float4*>(X + (size_t)b0 * DDIM);
        #pragma unroll
        for (int it = 0; it < 16; ++it) {
            int idx4 = tid + it * 256;
            int r = idx4 >> 6, c4 = idx4 & 63;
            float4 v = Xv[r * 64 + c4];
            uint2 p;
            p.x = (unsigned)f2bf(v.x) | ((unsigned)f2bf(v.y) << 16);
            p.y = (unsigned)f2bf(v.z) | ((unsigned)f2bf(v.w) << 16);
            int byte = (r * 512 + c4 * 8) ^ ((r & 7) << 4);
            *reinterpret_cast<uint2*>(&Xl[byte]) = p;
        }
    }
    f32x4 acc[4][4];
    #pragma unroll
    for (int nf = 0; nf < 4; ++nf) {
        int j = wv * 64 + nf * 16 + r15;
        float vj = Wn[(size_t)j * WROW + 256] + Wn[65792 + j];
        #pragma unroll
        for (int m = 0; m < 4; ++m) acc[m][nf] = f32x4{vj, vj, vj, vj};
    }
    auto stageW = [&](int buf, int kk) {
        const int k0 = kk * 32;
        const int j  = tid;
        float t[32];
        #pragma unroll
        for (int k = 0; k < 32; ++k) t[k] = Wn[(size_t)(k0 + k) * WROW + j];
        char* Wb = Wl[buf];
        #pragma unroll
        for (int g = 0; g < 4; ++g) {
            unsigned int p0 = (unsigned)f2bf(t[g*8+0]) | ((unsigned)f2bf(t[g*8+1]) << 16);
            unsigned int p1 = (unsigned)f2bf(t[g*8+2]) | ((unsigned)f2bf(t[g*8+3]) << 16);
            unsigned int p2 = (unsigned)f2bf(t[g*8+4]) | ((unsigned)f2bf(t[g*8+5]) << 16);
            unsigned int p3 = (unsigned)f2bf(t[g*8+6]) | ((unsigned)f2bf(t[g*8+7]) << 16);
            int byte = (j * 64 + g * 16) ^ ((j & 7) << 4);
            *reinterpret_cast<uint4*>(&Wb[byte]) = make_uint4(p0, p1, p2, p3);
        }
    };
    auto computeK = [&](int buf, int kk) {
        char* Wb = Wl[buf];
        short8 a[4], bbf[4];
        #pragma unroll
        for (int m = 0; m < 4; ++m) {
            int row = m * 16 + r15;
            int byte = (row * 512 + kk * 64 + qw * 16) ^ ((row & 7) << 4);
            a[m] = *reinterpret_cast<short8*>(&Xl[byte]);
        }
        #pragma unroll
        for (int nf = 0; nf < 4; ++nf) {
            int j = wv * 64 + nf * 16 + r15;
            int byte = (j * 64 + qw * 16) ^ ((j & 7) << 4);
            bbf[nf] = *reinterpret_cast<short8*>(&Wb[byte]);
        }
        #pragma unroll
        for (int m = 0; m < 4; ++m)
            #pragma unroll
            for (int nf = 0; nf < 4; ++nf)
                acc[m][nf] = __builtin_amdgcn_mfma_f32_16x16x32_bf16(a[m], bbf[nf], acc[m][nf], 0, 0, 0);
    };
    stageW(0, 0);
    int cur = 0;
    #pragma unroll
    for (int kk = 0; kk < 8; ++kk) {
        __syncthreads();
        if (kk < 7) stageW(cur ^ 1, kk + 1);
        computeK(cur, kk);
        cur ^= 1;
    }
    float ps[16];
    #pragma unroll
    for (int i = 0; i < 16; ++i) ps[i] = 0.f;
    #pragma unroll
    for (int m = 0; m < 4; ++m)
        #pragma unroll
        for (int nf = 0; nf < 4; ++nf) {
            int j = wv * 64 + nf * 16 + r15;
            #pragma unroll
            for (int r = 0; r < 4; ++r) {
                int brow = m * 16 + qw * 4 + r;
                int byte = (brow * 512 + j * 2) ^ ((brow & 7) << 4);
                float xv = bf2f(*reinterpret_cast<unsigned short*>(&Xl[byte]));
                ps[m * 4 + r] += acc[m][nf][r] * xv;
            }
        }
    #pragma unroll
    for (int off = 1; off <= 8; off <<= 1)
        #pragma unroll
        for (int i = 0; i < 16; ++i) ps[i] += __shfl_xor(ps[i], off, 64);
    __syncthreads();
    float* red = reinterpret_cast<float*>(Wl);
    if (r15 == 0) {
        #pragma unroll
        for (int m = 0; m < 4; ++m)
            #pragma unroll
            for (int r = 0; r < 4; ++r)
                red[wv * 64 + m * 16 + qw * 4 + r] = ps[m * 4 + r];
    }
    __syncthreads();
    if (tid < 64) {
        float s = red[tid] + red[64 + tid] + red[128 + tid] + red[192 + tid] + Wn[66048];
        H[(size_t)(b0 + tid) * DDIM + n] = s;
    }
}

__global__ __launch_bounds__(256) void out_kernel(
    const float* __restrict__ H, const float* __restrict__ w_out,
    const float* __restrict__ b_out, float* __restrict__ out)
{
    int b = blockIdx.x * 4 + (threadIdx.x >> 6);
    int lane = threadIdx.x & 63;
    const float* h = H + (size_t)b * 256;
    float s = 0.f;
    #pragma unroll
    for (int c = 0; c < 4; ++c) s += h[lane + c * 64] * w_out[lane + c * 64];
    #pragma unroll
    for (int off = 1; off < 64; off <<= 1) s += __shfl_xor(s, off, 64);
    if (lane == 0) out[b] = s + b_out[0];
}

extern "C" void kernel_launch(void* const* d_in, const int* in_sizes, int n_in,
                              void* d_out, int out_size, void* d_ws, size_t ws_size,
                              hipStream_t stream) {
    const float* x    = (const float*)d_in[0];
    const float* W1   = (const float*)d_in[1];
    const float* W2   = (const float*)d_in[2];
    const float* W3   = (const float*)d_in[3];
    const float* wout = (const float*)d_in[4];
    const float* bout = (const float*)d_in[5];
    float* out = (float*)d_out;

    const size_t WT3_BYTES = (size_t)256 * WT3_N * 2;      // 18.87 MB
    const size_t XB_BYTES  = (size_t)2048 * 256 * 2;       // 1 MB
    const size_t XE2_BYTES = (size_t)32 * 16384 * 2;       // 1 MB
    const size_t VT_BYTES  = 256 * 256 * 4;                // 256 KB
    const size_t DV_BYTES  = 1024;
    const size_t HT_BYTES  = (size_t)256 * 2048 * 2;       // 1 MB
    const size_t need = WT3_BYTES + XB_BYTES + XE2_BYTES + VT_BYTES + DV_BYTES + HT_BYTES; // ~22.1 MB

    dim3 blk(256, 1, 1);

    if (ws_size >= need) {
        char* p = (char*)d_ws;
        unsigned short* Wt3 = (unsigned short*)p;              p += WT3_BYTES;
        unsigned short* Xbf = (unsigned short*)p;              p += XB_BYTES;
        unsigned short* Xe2 = (unsigned short*)p;              p += XE2_BYTES;
        float*          Vt  = (float*)p;                       p += VT_BYTES;
        float*          Dv  = (float*)p;                       p += DV_BYTES;
        unsigned short* Ht  = (unsigned short*)p;

        const float* Ws[3] = {W1, W2, W3};

        dim3 wgrid(10, 256), lgrid(32, 32), xgrid(16);
        for (int L = 0; L < 3; ++L) {
            if (L == 0) conv_x_rm_kernel<<<xgrid, blk, 0, stream>>>(x, Xbf, Xe2);
            else        conv_x_tr_kernel<<<xgrid, blk, 0, stream>>>(Ht, Xbf, Xe2);
            conv_w3_kernel<<<wgrid, blk, 0, stream>>>(Ws[L], Wt3, Vt, Dv);
            pn13_kernel<<<lgrid, blk, 0, stream>>>(Xbf, Xe2, Wt3, Vt, Dv, Ht);
        }
        out_tr_kernel<<<xgrid, blk, 0, stream>>>(Ht, wout, bout, out);
    } else {
        float* h1 = (float*)d_ws;
        float* h2 = h1 + 2048 * 256;
        dim3 grid(32, 256);
        pn_layer_kernel<<<grid, blk, 0, stream>>>(x,  W1, h1);
        pn_layer_kernel<<<grid, blk, 0, stream>>>(h1, W2, h2);
        pn_layer_kernel<<<grid, blk, 0, stream>>>(h2, W3, h1);
        out_kernel<<<512, blk, 0, stream>>>(h1, wout, bout, out);
    }
}